// Round 3
// baseline (1013.064 us; speedup 1.0000x reference)
//
#include <hip/hip_runtime.h>
#include <stdint.h>

#define B_ 32
#define S_ 512
#define I_ 256
#define H_ 512
#define OUTW 1024
#define OUTS_ELEMS (B_*S_*OUTW)   // 16777216

typedef _Float16 f16;
typedef _Float16 half2_t __attribute__((ext_vector_type(2)));

__device__ __forceinline__ float fdot2(uint32_t a, uint32_t b, float c){
#if __has_builtin(__builtin_amdgcn_fdot2)
  return __builtin_amdgcn_fdot2(__builtin_bit_cast(half2_t, a),
                                __builtin_bit_cast(half2_t, b), c, false);
#else
  half2_t ha = __builtin_bit_cast(half2_t, a);
  half2_t hb = __builtin_bit_cast(half2_t, b);
  return c + (float)ha.x*(float)hb.x + (float)ha.y*(float)hb.y;
#endif
}

__device__ __forceinline__ uint32_t packf16(float x, float y){
  union { f16 h[2]; uint32_t u; } z;
  z.h[0] = (f16)x; z.h[1] = (f16)y;
  return z.u;
}

template<int CTRL>
__device__ __forceinline__ float dpp_xor_add(float x){
  int v = __builtin_amdgcn_update_dpp(0, __float_as_int(x), CTRL, 0xF, 0xF, true);
  return x + __int_as_float(v);
}

// full 8-lane (ks) reduce of 4 accs; returns total for row jg + 64*(ks&3)
__device__ __forceinline__ float reduce8(float a0, float a1, float a2, float a3, int k3){
  a0 = dpp_xor_add<0xB1>(a0); a1 = dpp_xor_add<0xB1>(a1);
  a2 = dpp_xor_add<0xB1>(a2); a3 = dpp_xor_add<0xB1>(a3);
  a0 = dpp_xor_add<0x4E>(a0); a1 = dpp_xor_add<0x4E>(a1);
  a2 = dpp_xor_add<0x4E>(a2); a3 = dpp_xor_add<0x4E>(a3);
  float own = (k3==0)?a0:(k3==1)?a1:(k3==2)?a2:a3;
  return own + __shfl_xor(own, 4);
}

// ---------------------------------------------------------------------------
// P0: W_hh fp32 -> f16 into d_ws
// ---------------------------------------------------------------------------
__global__ __launch_bounds__(256) void cvt_w_kernel(const float* __restrict__ wf,
                                                    const float* __restrict__ wb,
                                                    f16* __restrict__ out){
  int i = blockIdx.x*256 + threadIdx.x;
  const float* src = (i < 32768) ? wf : wb;
  int base = (i & 32767) * 8;
  float4 a = *(const float4*)(src + base);
  float4 c = *(const float4*)(src + base + 4);
  uint4 o;
  o.x = packf16(a.x, a.y); o.y = packf16(a.z, a.w);
  o.z = packf16(c.x, c.y); o.w = packf16(c.z, c.w);
  *(uint4*)(out + (size_t)i*8) = o;
}

// ---------------------------------------------------------------------------
// P1: xp staged into d_out (read once by rnn, then overwritten with h).
// ---------------------------------------------------------------------------
#define PTM 128
#define PTN 64
#define PTK 32
__global__ __launch_bounds__(256) void proj_kernel(
    const float* __restrict__ x,
    const float* __restrict__ wihf, const float* __restrict__ wihb,
    const float* __restrict__ bihf, const float* __restrict__ bhhf,
    const float* __restrict__ bihb, const float* __restrict__ bhhb,
    float* __restrict__ out)
{
  __shared__ float As[PTK][132];
  __shared__ float Bs[PTK][68];
  const int tid = threadIdx.x;
  const int row0 = blockIdx.x * PTM;
  const int j0   = blockIdx.y * PTN;
  const int dir  = (j0 >= 512) ? 1 : 0;
  const int jl0  = j0 - dir*512;
  const float* wih = dir ? wihb : wihf;
  const float* bi  = dir ? bihb : bihf;
  const float* bh  = dir ? bhhb : bhhf;

  const int ty = tid >> 4, tx = tid & 15;
  float acc[8][4];
#pragma unroll
  for (int i=0;i<8;i++)
#pragma unroll
    for (int j=0;j<4;j++) acc[i][j] = 0.f;

  float bias[4];
#pragma unroll
  for (int jj=0;jj<4;jj++){ int jl = jl0 + tx*4 + jj; bias[jj] = bi[jl] + bh[jl]; }

  for (int k0 = 0; k0 < I_; k0 += PTK){
    {
      int r = tid >> 1, kh = (tid & 1) * 16;
      int rg = row0 + r; int bb = rg & 31, tt = rg >> 5;
      const float* ap = x + ((size_t)bb*S_ + tt)*I_ + k0 + kh;
#pragma unroll
      for (int u=0;u<4;u++){
        float4 v = *(const float4*)(ap + u*4);
        As[kh+u*4+0][r] = v.x; As[kh+u*4+1][r] = v.y;
        As[kh+u*4+2][r] = v.z; As[kh+u*4+3][r] = v.w;
      }
    }
    {
      int jr = tid >> 2, kh = (tid & 3) * 8;
      const float* bp = wih + (size_t)(jl0 + jr)*I_ + k0 + kh;
#pragma unroll
      for (int u=0;u<2;u++){
        float4 v = *(const float4*)(bp + u*4);
        Bs[kh+u*4+0][jr] = v.x; Bs[kh+u*4+1][jr] = v.y;
        Bs[kh+u*4+2][jr] = v.z; Bs[kh+u*4+3][jr] = v.w;
      }
    }
    __syncthreads();
#pragma unroll 8
    for (int kk=0; kk<PTK; ++kk){
      const float4 a0 = *(const float4*)&As[kk][ty*8+0];
      const float4 a1 = *(const float4*)&As[kk][ty*8+4];
      const float4 bq = *(const float4*)&Bs[kk][tx*4];
      const float av[8] = {a0.x,a0.y,a0.z,a0.w,a1.x,a1.y,a1.z,a1.w};
      const float bv[4] = {bq.x,bq.y,bq.z,bq.w};
#pragma unroll
      for (int i=0;i<8;i++)
#pragma unroll
        for (int j=0;j<4;j++) acc[i][j] = fmaf(av[i], bv[j], acc[i][j]);
    }
    __syncthreads();
  }
#pragma unroll
  for (int i=0;i<8;i++){
    int rg = row0 + ty*8 + i; int bb = rg & 31, tt = rg >> 5;
    float* op = out + ((size_t)bb*S_ + tt)*OUTW + j0 + tx*4;
    float4 v = {acc[i][0]+bias[0], acc[i][1]+bias[1], acc[i][2]+bias[2], acc[i][3]+bias[3]};
    *(float4*)op = v;
  }
}

// ---------------------------------------------------------------------------
// R: partial-exchange recurrence. 128 WGs; pair p = blocks (p, p+64) -> SAME
// XCD under round-robin dispatch. half = blockIdx>>6, pairid = blockIdx&63,
// dir = pairid>>5, b = pairid&31. WG owns rows [half*256,+256) and k-columns
// [half*256,+256); weights (8 rows x 32k per lane = 128 u32 f16-pairs) are
// asm-pinned in VGPRs. Per step: phase A = partials for PARTNER's rows
// (publish immediately, tagged f16), phase B = partials for own rows; owner
// lane spins on its single partner dword, finalizes relu, writes h to LDS
// (XOR-swizzled, double-buffered 2x512B). One barrier per step. Only own h
// is ever needed locally -> 4 ds_read_b128/lane/step, reused by both phases.
// ---------------------------------------------------------------------------
#define MAIL_OFF_U32 (1u<<18)      // W f16 = 1 MB = 2^18 u32
#define MAIL_BYTES   (64*2*2*256*4)  // 256 KB

#define PIN16(A) asm volatile("" : \
  "+v"(A[0]),"+v"(A[1]),"+v"(A[2]),"+v"(A[3]),"+v"(A[4]),"+v"(A[5]),"+v"(A[6]),"+v"(A[7]), \
  "+v"(A[8]),"+v"(A[9]),"+v"(A[10]),"+v"(A[11]),"+v"(A[12]),"+v"(A[13]),"+v"(A[14]),"+v"(A[15]))

#define DOT4(ACC, WM, HV, Q) \
  ACC = fdot2(WM[Q*4+0], HV.x, ACC); ACC = fdot2(WM[Q*4+1], HV.y, ACC); \
  ACC = fdot2(WM[Q*4+2], HV.z, ACC); ACC = fdot2(WM[Q*4+3], HV.w, ACC);

#define PHASE16(W, A0,A1,A2,A3) \
  DOT4(A0, W[0], hv0, 0) DOT4(A0, W[0], hv1, 1) DOT4(A0, W[0], hv2, 2) DOT4(A0, W[0], hv3, 3) \
  DOT4(A1, W[1], hv0, 0) DOT4(A1, W[1], hv1, 1) DOT4(A1, W[1], hv2, 2) DOT4(A1, W[1], hv3, 3) \
  DOT4(A2, W[2], hv0, 0) DOT4(A2, W[2], hv1, 1) DOT4(A2, W[2], hv2, 2) DOT4(A2, W[2], hv3, 3) \
  DOT4(A3, W[3], hv0, 0) DOT4(A3, W[3], hv1, 1) DOT4(A3, W[3], hv2, 2) DOT4(A3, W[3], hv3, 3)

__global__ __launch_bounds__(512, 2) void rnn_kernel(
    const f16* __restrict__ Wall,   // [2][512][512] f16
    const float* __restrict__ h0,   // [2][32][512]
    float* dout, uint32_t* mailbase)
{
  __shared__ char lds[1024];        // 2 parity x 256 f16 (own-half h, swizzled)
  const int tid   = threadIdx.x;
  const int half  = blockIdx.x >> 6;
  const int pairid= blockIdx.x & 63;
  const int dir   = pairid >> 5;
  const int b     = pairid & 31;
  const int jg    = tid >> 3;
  const int ks    = tid & 7;
  const int k3    = ks & 3;
  const bool owner= (ks < 4);
  const int jl    = jg + 64*k3;     // row (within 256-block) this lane finalizes

  const f16* Wd = Wall + (size_t)dir * (H_*(size_t)H_);
  float* outs = dout + (size_t)b * (S_*OUTW);
  const int col = dir*512 + half*256 + jl;
  float* hn = dout + (size_t)OUTS_ELEMS + ((size_t)dir*B_ + b) * H_;

  uint32_t* mw = mailbase + ((size_t)pairid*2 + half) * 512;       // we write partner's rows here
  uint32_t* mr = mailbase + ((size_t)pairid*2 + (half^1)) * 512;   // partner writes our rows here

  // ---- weights: phase A = partner's rows, phase B = own rows; k = own half
  uint32_t wA[4][16], wB[4][16];
#pragma unroll
  for (int m=0;m<4;m++){
    const uint4* pA = (const uint4*)(Wd + (size_t)((half^1)*256 + jg + 64*m)*H_ + half*256 + ks*32);
    const uint4* pB = (const uint4*)(Wd + (size_t)( half*256     + jg + 64*m)*H_ + half*256 + ks*32);
#pragma unroll
    for (int q=0;q<4;q++){
      uint4 v = pA[q];
      wA[m][q*4+0]=v.x; wA[m][q*4+1]=v.y; wA[m][q*4+2]=v.z; wA[m][q*4+3]=v.w;
      uint4 u = pB[q];
      wB[m][q*4+0]=u.x; wB[m][q*4+1]=u.y; wB[m][q*4+2]=u.z; wB[m][q*4+3]=u.w;
    }
  }

  // h LDS layout: logical 16B chunk c (0..31) at physical chunk (c&3)*8 + (c>>2)
  // -> read addrs (q fixed): phys = q*8+ks -> bank group = ks, conflict-free.
  const int hwoff = (((jl>>3)&3)*8 + (jl>>5))*16 + (jl&7)*2;   // owner h write
  // ---- stage own-half h0 into parity-0 buffer
  if (tid < 256){
    int off = (((tid>>3)&3)*8 + (tid>>5))*16 + (tid&7)*2;
    *(f16*)(lds + off) = (f16)h0[((size_t)dir*B_ + b)*H_ + half*256 + tid];
  }
  __syncthreads();

  for (int s=0; s<S_; ++s){
    // pin the weights in VGPRs every iteration (defeats remat/AGPR demotion)
    PIN16(wA[0]); PIN16(wA[1]); PIN16(wA[2]); PIN16(wA[3]);
    PIN16(wB[0]); PIN16(wB[1]); PIN16(wB[2]); PIN16(wB[3]);

    const int P = s & 1;
    const int t = dir ? (S_-1-s) : s;
    const char* hb = lds + P*512;
    float* xo = outs + (size_t)t*OUTW;
    float xpv = 0.f;
    if (owner) xpv = xo[col];                       // long-latency, hidden by phases

    const uint4 hv0 = *(const uint4*)(hb +       ks*16);
    const uint4 hv1 = *(const uint4*)(hb + 128 + ks*16);
    const uint4 hv2 = *(const uint4*)(hb + 256 + ks*16);
    const uint4 hv3 = *(const uint4*)(hb + 384 + ks*16);

    // ---- phase A: partials for PARTNER's rows; publish ASAP
    {
      float a0=0.f, a1=0.f, a2=0.f, a3=0.f;
      PHASE16(wA, a0,a1,a2,a3)
      float totA = reduce8(a0,a1,a2,a3,k3);
      if (owner){
        uint16_t pb = __builtin_bit_cast(uint16_t, (f16)totA);
        uint32_t val = ((uint32_t)pb << 16) | (uint32_t)(s+1);
        __hip_atomic_store(&mw[P*256 + jl], val, __ATOMIC_RELAXED, __HIP_MEMORY_SCOPE_AGENT);
      }
    }
    // ---- phase B: partials for OWN rows
    float totB;
    {
      float b0=0.f, b1=0.f, b2=0.f, b3=0.f;
      PHASE16(wB, b0,b1,b2,b3)
      totB = reduce8(b0,b1,b2,b3,k3);
    }
    // ---- finalize: spin on our single partner dword, relu, store
    if (owner){
      const uint32_t tag = (uint32_t)(s+1);
      uint32_t v;
      do {
        v = __hip_atomic_load(&mr[P*256 + jl], __ATOMIC_RELAXED, __HIP_MEMORY_SCOPE_AGENT);
      } while ((v & 0xffffu) != tag);
      float rem = (float)__builtin_bit_cast(f16, (uint16_t)(v >> 16));
      float h = fmaxf(xpv + totB + rem, 0.f);
      xo[col] = h;                                   // overwrite xp slot
      if (s == S_-1) hn[half*256 + jl] = h;
      *(f16*)(lds + (P^1)*512 + hwoff) = (f16)h;
    }
    asm volatile("s_waitcnt lgkmcnt(0)" ::: "memory");
    __builtin_amdgcn_s_barrier();
  }
}

// ---------------------------------------------------------------------------
extern "C" void kernel_launch(void* const* d_in, const int* in_sizes, int n_in,
                              void* d_out, int out_size, void* d_ws, size_t ws_size,
                              hipStream_t stream){
  const float* x    = (const float*)d_in[0];
  const float* h0   = (const float*)d_in[1];
  const float* wihf = (const float*)d_in[2];
  const float* whhf = (const float*)d_in[3];
  const float* bihf = (const float*)d_in[4];
  const float* bhhf = (const float*)d_in[5];
  const float* wihb = (const float*)d_in[6];
  const float* whhb = (const float*)d_in[7];
  const float* bihb = (const float*)d_in[8];
  const float* bhhb = (const float*)d_in[9];
  float* out = (float*)d_out;
  f16* wf16 = (f16*)d_ws;                            // 1 MB
  uint32_t* mail = (uint32_t*)d_ws + MAIL_OFF_U32;   // 256 KB

  hipMemsetAsync((void*)mail, 0, MAIL_BYTES, stream);  // kill stale tags across replays
  cvt_w_kernel<<<256, 256, 0, stream>>>(whhf, whhb, wf16);
  proj_kernel<<<dim3(128, 16), 256, 0, stream>>>(x, wihf, wihb, bihf, bhhf, bihb, bhhb, out);
  rnn_kernel<<<128, 512, 0, stream>>>(wf16, h0, out, mail);
}